// Round 9
// baseline (335.106 us; speedup 1.0000x reference)
//
#include <hip/hip_runtime.h>
#include <stdint.h>

#define DEVI __device__ __forceinline__

typedef short bf16x8 __attribute__((ext_vector_type(8)));
typedef float f32x4  __attribute__((ext_vector_type(4)));

DEVI short f2bf(float f){
  union { float f; uint32_t u; } un; un.f = f;
  uint32_t u = un.u;
  u += 0x7fffu + ((u >> 16) & 1u);   // RNE
  return (short)(u >> 16);
}
DEVI float bf2f(uint32_t us){
  union { uint32_t u; float f; } x; x.u = us << 16; return x.f;
}

DEVI f32x4 mfma16(bf16x8 a, bf16x8 b, f32x4 c){
  return __builtin_amdgcn_mfma_f32_16x16x32_bf16(a, b, c, 0, 0, 0);
}

// ---------- prep: transpose fp32 [R][C] -> bf16 [C][R] ----------
__global__ void transpose_bf(const float* __restrict__ W, short* __restrict__ WT,
                             int R, int C){
  __shared__ float tile[32][33];
  int ctiles = C >> 5;
  int bi = blockIdx.x / ctiles, bj = blockIdx.x % ctiles;
  int tx = threadIdx.x & 31, ty = threadIdx.x >> 5;
  #pragma unroll
  for (int r = 0; r < 4; ++r){
    int i = bi*32 + ty + r*8;
    tile[ty + r*8][tx] = W[(size_t)i*C + bj*32 + tx];
  }
  __syncthreads();
  #pragma unroll
  for (int r = 0; r < 4; ++r){
    int j = bj*32 + ty + r*8;
    WT[(size_t)j*R + bi*32 + tx] = f2bf(tile[tx][ty + r*8]);
  }
}

// ---------- prep: hvb = bf16(h_v * V), ub = bf16(u) ----------
__global__ void prep_hv(const float* __restrict__ hv, const float* __restrict__ V,
                        const float* __restrict__ u, short* __restrict__ hvb,
                        short* __restrict__ ub){
  int idx = blockIdx.x*256 + threadIdx.x;
  if (idx < 512*256){
    int r = idx >> 8;
    hvb[idx] = f2bf(hv[idx] * V[r]);
  } else if (idx < 512*256 + 1024){
    int i2 = idx - 512*256;
    ub[i2] = f2bf(u[i2]);
  }
}

// ---------- prep: s[(k,n)][j] = hv*W1[0:256] + u*W1[512:768] + b1   (bf16, row-major)
//                  tT[j][(k,m)] = hv*W1[256:512]                     (bf16, TRANSPOSED)
// Outputs staged through LDS so global writes are full-line coalesced.
__global__ __launch_bounds__(256) void prep_st(
    const short* __restrict__ hvb, const short* __restrict__ ub,
    const short* __restrict__ w1t, const float* __restrict__ b1,
    short* __restrict__ sbuf, short* __restrict__ tbuf)
{
  const int bid = blockIdx.x;
  const int st = bid >> 7;           // 0 = s, 1 = t
  const int rt8 = (bid >> 4) & 7;    // 8 row tiles of 64 over 512 rows
  const int ctile = bid & 15;        // 16 col tiles of 64 over 1024 cols
  const int r0 = rt8 << 6, j0 = ctile << 6;
  const int tid = threadIdx.x;
  const int w = tid >> 6, l = tid & 63;
  const int l15 = l & 15, l4 = l >> 4;
  __shared__ short A[64*256];
  __shared__ short Stile[64][64];
  for (int q = 0; q < 8; ++q){
    int id = tid + (q << 8);
    int row = id >> 5, c8 = id & 31;
    bf16x8 v = *(const bf16x8*)(hvb + (size_t)(r0 + row)*256 + c8*8);
    *(bf16x8*)((char*)A + row*512 + ((c8*16) ^ ((row & 7) << 4))) = v;
  }
  __syncthreads();
  const int wr = w >> 1, wc = w & 1;
  const int rowbase = wr << 5, colbase = wc << 5;
  const int swzA = (l15 & 7) << 4;
  f32x4 acc[2][2];
  acc[0][0]=0; acc[0][1]=0; acc[1][0]=0; acc[1][1]=0;
  const int ioff = st ? 256 : 0;
  const short* w1p = w1t + (size_t)(j0 + colbase + l15)*1024 + ioff + l4*8;
  const char* ap0 = (const char*)A + (rowbase + l15)*512;
  const char* ap1 = ap0 + 16*512;
  #pragma unroll
  for (int kk = 0; kk < 8; ++kk){
    int ib = kk*64 + l4*16;
    bf16x8 a0 = *(const bf16x8*)(ap0 + (ib ^ swzA));
    bf16x8 a1 = *(const bf16x8*)(ap1 + (ib ^ swzA));
    bf16x8 b0 = *(const bf16x8*)(w1p + kk*32);
    bf16x8 b1v = *(const bf16x8*)(w1p + 16*1024 + kk*32);
    acc[0][0] = mfma16(a0, b0, acc[0][0]);
    acc[1][0] = mfma16(a1, b0, acc[1][0]);
    acc[0][1] = mfma16(a0, b1v, acc[0][1]);
    acc[1][1] = mfma16(a1, b1v, acc[1][1]);
  }
  if (st == 0){
    const int kb = r0 >> 7;
    const short* up = ub + kb*256 + l4*8;
    const short* w1pu = w1t + (size_t)(j0 + colbase + l15)*1024 + 512 + l4*8;
    #pragma unroll
    for (int kk = 0; kk < 8; ++kk){
      bf16x8 au = *(const bf16x8*)(up + kk*32);
      bf16x8 b0 = *(const bf16x8*)(w1pu + kk*32);
      bf16x8 b1v = *(const bf16x8*)(w1pu + 16*1024 + kk*32);
      acc[0][0] = mfma16(au, b0, acc[0][0]);
      acc[1][0] = mfma16(au, b0, acc[1][0]);
      acc[0][1] = mfma16(au, b1v, acc[0][1]);
      acc[1][1] = mfma16(au, b1v, acc[1][1]);
    }
  }
  // stage into LDS: st==0 -> Stile[row][j], st==1 -> Stile[j][row]
  #pragma unroll
  for (int r = 0; r < 2; ++r){
    #pragma unroll
    for (int c = 0; c < 2; ++c){
      int jl = colbase + c*16 + l15;
      float badd = st ? 0.f : b1[j0 + jl];
      #pragma unroll
      for (int reg = 0; reg < 4; ++reg){
        int rowl = rowbase + r*16 + l4*4 + reg;
        short v = f2bf(acc[r][c][reg] + badd);
        if (st == 0) Stile[rowl][jl] = v;
        else         Stile[jl][rowl] = v;
      }
    }
  }
  __syncthreads();
  // coalesced write-out: thread tid handles row a = tid>>2, 16-elem chunk (tid&3)
  {
    int a = tid >> 2, ch = (tid & 3) << 4;
    bf16x8 v0 = *(const bf16x8*)(&Stile[a][ch]);
    bf16x8 v1 = *(const bf16x8*)(&Stile[a][ch + 8]);
    short* dst = (st == 0)
      ? (sbuf + (size_t)(r0 + a)*1024 + j0 + ch)
      : (tbuf + (size_t)(j0 + a)*512  + r0 + ch);
    *(bf16x8*)(dst)     = v0;
    *(bf16x8*)(dst + 8) = v1;
  }
}

// ---------- main fused kernel ----------
// block = (k, n, m-half): 64 rows (m), full 256 outputs. 4 waves.
// __launch_bounds__(256,3): cap ~170 regs (VGPR+AGPR); (256,4) caused spills (R6/R7).
// Loop: dbuf eluv + ONE barrier per jc (R5 structure, race-free by wave-skew bound).
// bw2a AND bw2b both loaded before the barrier (L2 latency cover); bw1/t4 pipelined.
// Epilogue: LDS-bounce per 16-row chunk -> full-line coalesced fp32 stores
// (fixes 110MB partial-line RMW write amplification seen in R8).
__global__ __launch_bounds__(256, 3) void fused_edge(
    const float* __restrict__ he, const unsigned short* __restrict__ sb,
    const unsigned short* __restrict__ tbT, const short* __restrict__ w1t,
    const short* __restrict__ w2t, const float* __restrict__ b2,
    const int* __restrict__ Em, float* __restrict__ out)
{
  const int b = blockIdx.x;
  const int k = b >> 8;
  const int n = (b >> 1) & 127;
  const int m0 = (b & 1) << 6;
  const int tid = threadIdx.x;
  const int w = tid >> 6, l = tid & 63;
  const int l15 = l & 15, l4 = l >> 4;

  __shared__ short heb[64*256];      // bf16 h_e tile, XOR-swizzled  (32 KB)
  __shared__ short eluv[2][4160];    // dbuf ELU chunk (+pad reused as fp32 stage) 16.25KB
  __shared__ int   emask[64];        // E[..,1] per row              (256 B)

  const int grow0 = ((k << 7) + n)*128 + m0;
  const float* hesrc = he + (size_t)grow0 * 256;

  // stage h_e[k,n,m0:m0+64,:] -> bf16 LDS (swizzled)
  #pragma unroll
  for (int q = 0; q < 8; ++q){
    int id = tid + (q << 8);
    int row = id >> 5, c8 = id & 31;
    const float4* p = (const float4*)(hesrc + row*256 + c8*8);
    float4 a4 = p[0], b4 = p[1];
    union { bf16x8 v; short s[8]; } pk;
    pk.s[0]=f2bf(a4.x); pk.s[1]=f2bf(a4.y); pk.s[2]=f2bf(a4.z); pk.s[3]=f2bf(a4.w);
    pk.s[4]=f2bf(b4.x); pk.s[5]=f2bf(b4.y); pk.s[6]=f2bf(b4.z); pk.s[7]=f2bf(b4.w);
    *(bf16x8*)((char*)heb + row*512 + ((c8*16) ^ ((row & 7) << 4))) = pk.v;
  }
  if (tid < 64) emask[tid] = Em[(size_t)(grow0 + tid)*2 + 1];
  __syncthreads();

  f32x4 acc2[4][4];
  #pragma unroll
  for (int i = 0; i < 4; ++i)
    #pragma unroll
    for (int j = 0; j < 4; ++j) acc2[i][j] = 0;

  const unsigned short* srow = sb  + (size_t)((k << 7) + n)*1024;
  const unsigned short* tcol = tbT + (size_t)((k << 7) + m0);   // tT[j][512] base at m0
  const char* hb = (const char*)heb;
  const int swz = (l15 & 7) << 4;

  union u4 { ushort4 v; unsigned short s[4]; };

  // ---- prologue: loads for jc = 0 ----
  bf16x8 bw1[8];
  {
    const short* w1p = w1t + (size_t)(w*16 + l15)*1024 + 768 + l4*8;
    #pragma unroll
    for (int kk = 0; kk < 8; ++kk) bw1[kk] = *(const bf16x8*)(w1p + kk*32);
  }
  u4 t4[4];
  #pragma unroll
  for (int rt = 0; rt < 4; ++rt)
    t4[rt].v = *(const ushort4*)(tcol + (size_t)(w*16 + l15)*512 + rt*16 + l4*4);
  float sv = bf2f(srow[w*16 + l15]);

  #pragma unroll
  for (int jc = 0; jc < 16; ++jc){
    const int jcol = jc*64 + w*16 + l15;

    // ---- GEMM1: z1[64 x 16(w)] = heb @ W1[768:1024, jcol] ----
    f32x4 acc1[4];
    acc1[0]=0; acc1[1]=0; acc1[2]=0; acc1[3]=0;
    __builtin_amdgcn_s_setprio(1);
    #pragma unroll
    for (int kk = 0; kk < 8; ++kk){
      int ib = kk*64 + l4*16;
      #pragma unroll
      for (int rt = 0; rt < 4; ++rt){
        int row = rt*16 + l15;
        bf16x8 a = *(const bf16x8*)(hb + row*512 + (ib ^ swz));
        acc1[rt] = mfma16(a, bw1[kk], acc1[rt]);
      }
    }
    __builtin_amdgcn_s_setprio(0);

    // ---- issue BOTH W2 halves (consumed after barrier; full L2-latency cover) ----
    const short* w2p = w2t + (size_t)(w*64 + l15)*1024 + jc*64 + l4*8;
    bf16x8 bw2a[4], bw2b[4];
    #pragma unroll
    for (int q = 0; q < 4; ++q){
      bw2a[q] = *(const bf16x8*)(w2p + (size_t)q*16*1024);
      bw2b[q] = *(const bf16x8*)(w2p + (size_t)q*16*1024 + 32);
    }

    // ---- reload bw1 for jc+1 (regs dead after GEMM1) ----
    if (jc < 15){
      const short* w1p = w1t + (size_t)(jcol + 64)*1024 + 768 + l4*8;
      #pragma unroll
      for (int kk = 0; kk < 8; ++kk) bw1[kk] = *(const bf16x8*)(w1p + kk*32);
    }

    // ---- ELU: z1 + s + t, write bf16 to LDS dbuf (swizzled) ----
    char* eb = (char*)(&eluv[jc & 1][0]);
    #pragma unroll
    for (int rt = 0; rt < 4; ++rt){
      #pragma unroll
      for (int reg = 0; reg < 4; ++reg){
        int row = rt*16 + l4*4 + reg;
        float v = acc1[rt][reg] + sv + bf2f(t4[rt].s[reg]);
        v = v > 0.f ? v : (__expf(v) - 1.f);
        *(short*)(eb + row*128 + ((((w*16 + l15)*2)) ^ ((row & 7) << 4))) = f2bf(v);
      }
    }

    // ---- reload t4/sv for jc+1 ----
    if (jc < 15){
      #pragma unroll
      for (int rt = 0; rt < 4; ++rt)
        t4[rt].v = *(const ushort4*)(tcol + (size_t)(jcol + 64)*512 + rt*16 + l4*4);
      sv = bf2f(srow[jcol + 64]);
    }
    __syncthreads();   // eluv[jc&1] ready (single barrier per jc; dbuf protects reuse)

    // ---- GEMM2: acc2 += ELU-chunk @ W2[jc*64:+64, w*64:+64] ----
    __builtin_amdgcn_s_setprio(1);
    {
      int jb = l4*16;
      #pragma unroll
      for (int rt = 0; rt < 4; ++rt){
        int row = rt*16 + l15;
        bf16x8 a2 = *(const bf16x8*)(eb + row*128 + (jb ^ swz));
        #pragma unroll
        for (int q = 0; q < 4; ++q)
          acc2[rt][q] = mfma16(a2, bw2a[q], acc2[rt][q]);
      }
      jb = 64 + l4*16;
      #pragma unroll
      for (int rt = 0; rt < 4; ++rt){
        int row = rt*16 + l15;
        bf16x8 a2 = *(const bf16x8*)(eb + row*128 + (jb ^ swz));
        #pragma unroll
        for (int q = 0; q < 4; ++q)
          acc2[rt][q] = mfma16(a2, bw2b[q], acc2[rt][q]);
      }
    }
    __builtin_amdgcn_s_setprio(0);
  }

  // ---- epilogue: + b2, E-mask, residual from LDS heb, LDS-bounce coalesced store ----
  float bias[4];
  #pragma unroll
  for (int q = 0; q < 4; ++q) bias[q] = b2[w*64 + q*16 + l15];
  float* stage = (float*)(&eluv[0][0]);   // 16 rows x 260 floats (16.25 KB)

  #pragma unroll
  for (int rt = 0; rt < 4; ++rt){
    __syncthreads();   // eluv free (GEMM2(15) reads done / prev rt reads done)
    #pragma unroll
    for (int reg = 0; reg < 4; ++reg){
      int rr  = l4*4 + reg;            // row within 16-row chunk
      int row = rt*16 + rr;            // row within 64-row tile
      int e = emask[row];
      const char* hrow = hb + row*512;
      int sw = (row & 7) << 4;
      #pragma unroll
      for (int q = 0; q < 4; ++q){
        int col = w*64 + q*16 + l15;
        float hv = bf2f(*(const unsigned short*)(hrow + ((col*2) ^ sw)));
        float v = (e == 1) ? (acc2[rt][q][reg] + bias[q]) : 0.f;
        stage[rr*260 + col] = v + hv;  // stride 260: conflict-free (all 32 banks, 2-way)
      }
    }
    __syncthreads();   // stage ready
    {
      int rr = tid >> 4, c0 = (tid & 15) << 4;
      const f32x4* sp = (const f32x4*)(stage + rr*260 + c0);
      f32x4 v0 = sp[0], v1 = sp[1], v2 = sp[2], v3 = sp[3];
      f32x4* op = (f32x4*)(out + (size_t)(grow0 + rt*16 + rr)*256 + c0);
      op[0] = v0; op[1] = v1; op[2] = v2; op[3] = v3;   // 64B/thread, full lines
    }
  }
}

extern "C" void kernel_launch(void* const* d_in, const int* in_sizes, int n_in,
                              void* d_out, int out_size, void* d_ws, size_t ws_size,
                              hipStream_t stream)
{
  const float* u   = (const float*)d_in[0];
  const float* h_v = (const float*)d_in[1];
  const float* h_e = (const float*)d_in[2];
  const float* V   = (const float*)d_in[3];
  const int*   E   = (const int*)d_in[4];
  const float* W1  = (const float*)d_in[5];
  const float* b1  = (const float*)d_in[6];
  const float* W2  = (const float*)d_in[7];
  const float* b2  = (const float*)d_in[8];
  float* out = (float*)d_out;

  char* ws = (char*)d_ws;
  short* w1t  = (short*)(ws);                               // 2 MB   bf16 W1^T [1024][1024]
  short* w2t  = (short*)(ws + (2u<<20));                    // 512KB  bf16 W2^T [256][1024]
  short* hvb  = (short*)(ws + (2u<<20) + (512u<<10));       // 256KB  bf16 masked h_v
  short* ub   = (short*)(ws + (2u<<20) + (768u<<10));       // 2KB    bf16 u
  short* sbuf = (short*)(ws + (3u<<20));                    // 1 MB   bf16 s [512][1024]
  short* tbuf = (short*)(ws + (4u<<20));                    // 1 MB   bf16 tT [1024][512]

  transpose_bf<<<1024, 256, 0, stream>>>(W1, w1t, 1024, 1024);
  transpose_bf<<<256,  256, 0, stream>>>(W2, w2t, 1024, 256);
  prep_hv<<<516, 256, 0, stream>>>(h_v, V, u, hvb, ub);
  prep_st<<<256, 256, 0, stream>>>(hvb, ub, w1t, b1, sbuf, tbuf);
  fused_edge<<<1024, 256, 0, stream>>>(h_e,
                                       (const unsigned short*)sbuf,
                                       (const unsigned short*)tbuf,
                                       w1t, w2t, b2, E, out);
}

// Round 10
// 214.947 us; speedup vs baseline: 1.5590x; 1.5590x over previous
//
#include <hip/hip_runtime.h>
#include <stdint.h>

#define DEVI __device__ __forceinline__

typedef short bf16x8 __attribute__((ext_vector_type(8)));
typedef float f32x4  __attribute__((ext_vector_type(4)));

DEVI short f2bf(float f){
  union { float f; uint32_t u; } un; un.f = f;
  uint32_t u = un.u;
  u += 0x7fffu + ((u >> 16) & 1u);   // RNE
  return (short)(u >> 16);
}
DEVI float bf2f(uint32_t us){
  union { uint32_t u; float f; } x; x.u = us << 16; return x.f;
}

DEVI f32x4 mfma16(bf16x8 a, bf16x8 b, f32x4 c){
  return __builtin_amdgcn_mfma_f32_16x16x32_bf16(a, b, c, 0, 0, 0);
}

// ---------- prep: transpose fp32 [R][C] -> bf16 [C][R] ----------
__global__ void transpose_bf(const float* __restrict__ W, short* __restrict__ WT,
                             int R, int C){
  __shared__ float tile[32][33];
  int ctiles = C >> 5;
  int bi = blockIdx.x / ctiles, bj = blockIdx.x % ctiles;
  int tx = threadIdx.x & 31, ty = threadIdx.x >> 5;
  #pragma unroll
  for (int r = 0; r < 4; ++r){
    int i = bi*32 + ty + r*8;
    tile[ty + r*8][tx] = W[(size_t)i*C + bj*32 + tx];
  }
  __syncthreads();
  #pragma unroll
  for (int r = 0; r < 4; ++r){
    int j = bj*32 + ty + r*8;
    WT[(size_t)j*R + bi*32 + tx] = f2bf(tile[tx][ty + r*8]);
  }
}

// ---------- prep: hvb = bf16(h_v * V), ub = bf16(u) ----------
__global__ void prep_hv(const float* __restrict__ hv, const float* __restrict__ V,
                        const float* __restrict__ u, short* __restrict__ hvb,
                        short* __restrict__ ub){
  int idx = blockIdx.x*256 + threadIdx.x;
  if (idx < 512*256){
    int r = idx >> 8;
    hvb[idx] = f2bf(hv[idx] * V[r]);
  } else if (idx < 512*256 + 1024){
    int i2 = idx - 512*256;
    ub[i2] = f2bf(u[i2]);
  }
}

// ---------- prep: s[(k,n)][j] = hv*W1[0:256] + u*W1[512:768] + b1   (bf16, row-major)
//                  tT[j][(k,m)] = hv*W1[256:512]                     (bf16, TRANSPOSED)
// Outputs staged through LDS so global writes are full-line coalesced.
__global__ __launch_bounds__(256) void prep_st(
    const short* __restrict__ hvb, const short* __restrict__ ub,
    const short* __restrict__ w1t, const float* __restrict__ b1,
    short* __restrict__ sbuf, short* __restrict__ tbuf)
{
  const int bid = blockIdx.x;
  const int st = bid >> 7;           // 0 = s, 1 = t
  const int rt8 = (bid >> 4) & 7;    // 8 row tiles of 64 over 512 rows
  const int ctile = bid & 15;        // 16 col tiles of 64 over 1024 cols
  const int r0 = rt8 << 6, j0 = ctile << 6;
  const int tid = threadIdx.x;
  const int w = tid >> 6, l = tid & 63;
  const int l15 = l & 15, l4 = l >> 4;
  __shared__ short A[64*256];
  __shared__ short Stile[64][64];
  for (int q = 0; q < 8; ++q){
    int id = tid + (q << 8);
    int row = id >> 5, c8 = id & 31;
    bf16x8 v = *(const bf16x8*)(hvb + (size_t)(r0 + row)*256 + c8*8);
    *(bf16x8*)((char*)A + row*512 + ((c8*16) ^ ((row & 7) << 4))) = v;
  }
  __syncthreads();
  const int wr = w >> 1, wc = w & 1;
  const int rowbase = wr << 5, colbase = wc << 5;
  const int swzA = (l15 & 7) << 4;
  f32x4 acc[2][2];
  acc[0][0]=0; acc[0][1]=0; acc[1][0]=0; acc[1][1]=0;
  const int ioff = st ? 256 : 0;
  const short* w1p = w1t + (size_t)(j0 + colbase + l15)*1024 + ioff + l4*8;
  const char* ap0 = (const char*)A + (rowbase + l15)*512;
  const char* ap1 = ap0 + 16*512;
  #pragma unroll
  for (int kk = 0; kk < 8; ++kk){
    int ib = kk*64 + l4*16;
    bf16x8 a0 = *(const bf16x8*)(ap0 + (ib ^ swzA));
    bf16x8 a1 = *(const bf16x8*)(ap1 + (ib ^ swzA));
    bf16x8 b0 = *(const bf16x8*)(w1p + kk*32);
    bf16x8 b1v = *(const bf16x8*)(w1p + 16*1024 + kk*32);
    acc[0][0] = mfma16(a0, b0, acc[0][0]);
    acc[1][0] = mfma16(a1, b0, acc[1][0]);
    acc[0][1] = mfma16(a0, b1v, acc[0][1]);
    acc[1][1] = mfma16(a1, b1v, acc[1][1]);
  }
  if (st == 0){
    const int kb = r0 >> 7;
    const short* up = ub + kb*256 + l4*8;
    const short* w1pu = w1t + (size_t)(j0 + colbase + l15)*1024 + 512 + l4*8;
    #pragma unroll
    for (int kk = 0; kk < 8; ++kk){
      bf16x8 au = *(const bf16x8*)(up + kk*32);
      bf16x8 b0 = *(const bf16x8*)(w1pu + kk*32);
      bf16x8 b1v = *(const bf16x8*)(w1pu + 16*1024 + kk*32);
      acc[0][0] = mfma16(au, b0, acc[0][0]);
      acc[1][0] = mfma16(au, b0, acc[1][0]);
      acc[0][1] = mfma16(au, b1v, acc[0][1]);
      acc[1][1] = mfma16(au, b1v, acc[1][1]);
    }
  }
  // stage into LDS: st==0 -> Stile[row][j], st==1 -> Stile[j][row]
  #pragma unroll
  for (int r = 0; r < 2; ++r){
    #pragma unroll
    for (int c = 0; c < 2; ++c){
      int jl = colbase + c*16 + l15;
      float badd = st ? 0.f : b1[j0 + jl];
      #pragma unroll
      for (int reg = 0; reg < 4; ++reg){
        int rowl = rowbase + r*16 + l4*4 + reg;
        short v = f2bf(acc[r][c][reg] + badd);
        if (st == 0) Stile[rowl][jl] = v;
        else         Stile[jl][rowl] = v;
      }
    }
  }
  __syncthreads();
  // coalesced write-out: thread tid handles row a = tid>>2, 16-elem chunk (tid&3)
  {
    int a = tid >> 2, ch = (tid & 3) << 4;
    bf16x8 v0 = *(const bf16x8*)(&Stile[a][ch]);
    bf16x8 v1 = *(const bf16x8*)(&Stile[a][ch + 8]);
    short* dst = (st == 0)
      ? (sbuf + (size_t)(r0 + a)*1024 + j0 + ch)
      : (tbuf + (size_t)(j0 + a)*512  + r0 + ch);
    *(bf16x8*)(dst)     = v0;
    *(bf16x8*)(dst + 8) = v1;
  }
}

// ---------- main fused kernel (R5 structure, proven 209us) ----------
// block = (k, n, m-half) after XCD swizzle: each XCD gets 128 contiguous blocks
// (one k-quarter) -> per-XCD L2 working set ~1.3MB (weights + that k's s/t).
// 4 waves; dbuf eluv, ONE barrier per jc (race-free by wave-skew bound).
// h_e staging uses non-temporal (evict-first) loads so streaming data does not
// evict the weight working set from L2 (R6's failure was NT *stores*).
__global__ __launch_bounds__(256, 3) void fused_edge(
    const float* __restrict__ he, const unsigned short* __restrict__ sb,
    const unsigned short* __restrict__ tbT, const short* __restrict__ w1t,
    const short* __restrict__ w2t, const float* __restrict__ b2,
    const int* __restrict__ Em, float* __restrict__ out)
{
  const int bo = blockIdx.x;
  const int b = ((bo & 7) << 7) | (bo >> 3);   // XCD-aware swizzle (bijective, 1024%8==0)
  const int k = b >> 8;
  const int n = (b >> 1) & 127;
  const int m0 = (b & 1) << 6;
  const int tid = threadIdx.x;
  const int w = tid >> 6, l = tid & 63;
  const int l15 = l & 15, l4 = l >> 4;

  __shared__ short heb[64*256];      // bf16 h_e tile, XOR-swizzled  (32 KB)
  __shared__ short eluv[2][64*64];   // double-buffered ELU chunk    (16 KB) -> 48 KB

  const int grow0 = ((k << 7) + n)*128 + m0;
  const float* hesrc = he + (size_t)grow0 * 256;

  // stage h_e[k,n,m0:m0+64,:] -> bf16 LDS (swizzled); NT = evict-first in L2
  #pragma unroll
  for (int q = 0; q < 8; ++q){
    int id = tid + (q << 8);
    int row = id >> 5, c8 = id & 31;
    const f32x4* p = (const f32x4*)(hesrc + row*256 + c8*8);
    f32x4 a4 = __builtin_nontemporal_load(p);
    f32x4 b4 = __builtin_nontemporal_load(p + 1);
    union { bf16x8 v; short s[8]; } pk;
    pk.s[0]=f2bf(a4.x); pk.s[1]=f2bf(a4.y); pk.s[2]=f2bf(a4.z); pk.s[3]=f2bf(a4.w);
    pk.s[4]=f2bf(b4.x); pk.s[5]=f2bf(b4.y); pk.s[6]=f2bf(b4.z); pk.s[7]=f2bf(b4.w);
    *(bf16x8*)((char*)heb + row*512 + ((c8*16) ^ ((row & 7) << 4))) = pk.v;
  }
  __syncthreads();

  f32x4 acc2[4][4];
  #pragma unroll
  for (int i = 0; i < 4; ++i)
    #pragma unroll
    for (int j = 0; j < 4; ++j) acc2[i][j] = 0;

  const unsigned short* srow = sb  + (size_t)((k << 7) + n)*1024;
  const unsigned short* tcol = tbT + (size_t)((k << 7) + m0);   // tT[j][512] base at m0
  const char* hb = (const char*)heb;
  const int swz = (l15 & 7) << 4;

  union u4 { ushort4 v; unsigned short s[4]; };

  // ---- prologue: loads for jc = 0 ----
  bf16x8 bw1[8];
  {
    const short* w1p = w1t + (size_t)(w*16 + l15)*1024 + 768 + l4*8;
    #pragma unroll
    for (int kk = 0; kk < 8; ++kk) bw1[kk] = *(const bf16x8*)(w1p + kk*32);
  }
  u4 t4[4];
  #pragma unroll
  for (int rt = 0; rt < 4; ++rt)
    t4[rt].v = *(const ushort4*)(tcol + (size_t)(w*16 + l15)*512 + rt*16 + l4*4);
  float sv = bf2f(srow[w*16 + l15]);

  #pragma unroll
  for (int jc = 0; jc < 16; ++jc){
    const int jcol = jc*64 + w*16 + l15;

    // ---- GEMM1: z1[64 x 16(w)] = heb @ W1[768:1024, jcol] ----
    f32x4 acc1[4];
    acc1[0]=0; acc1[1]=0; acc1[2]=0; acc1[3]=0;
    #pragma unroll
    for (int kk = 0; kk < 8; ++kk){
      int ib = kk*64 + l4*16;
      #pragma unroll
      for (int rt = 0; rt < 4; ++rt){
        int row = rt*16 + l15;
        bf16x8 a = *(const bf16x8*)(hb + row*512 + (ib ^ swz));
        acc1[rt] = mfma16(a, bw1[kk], acc1[rt]);
      }
    }

    // ---- issue W2 first half (consumed after barrier; hidden under ELU) ----
    const short* w2p = w2t + (size_t)(w*64 + l15)*1024 + jc*64 + l4*8;
    bf16x8 bw2a[4];
    #pragma unroll
    for (int q = 0; q < 4; ++q)
      bw2a[q] = *(const bf16x8*)(w2p + (size_t)q*16*1024);

    // ---- reload bw1 for jc+1 (regs dead after GEMM1) ----
    if (jc < 15){
      const short* w1p = w1t + (size_t)(jcol + 64)*1024 + 768 + l4*8;
      #pragma unroll
      for (int kk = 0; kk < 8; ++kk) bw1[kk] = *(const bf16x8*)(w1p + kk*32);
    }

    // ---- ELU: z1 + s + t, write bf16 to LDS dbuf (swizzled) ----
    char* eb = (char*)(&eluv[jc & 1][0]);
    #pragma unroll
    for (int rt = 0; rt < 4; ++rt){
      #pragma unroll
      for (int reg = 0; reg < 4; ++reg){
        int row = rt*16 + l4*4 + reg;
        float v = acc1[rt][reg] + sv + bf2f(t4[rt].s[reg]);
        v = v > 0.f ? v : (__expf(v) - 1.f);
        *(short*)(eb + row*128 + ((((w*16 + l15)*2)) ^ ((row & 7) << 4))) = f2bf(v);
      }
    }

    // ---- reload t4/sv for jc+1 ----
    if (jc < 15){
      #pragma unroll
      for (int rt = 0; rt < 4; ++rt)
        t4[rt].v = *(const ushort4*)(tcol + (size_t)(jcol + 64)*512 + rt*16 + l4*4);
      sv = bf2f(srow[jcol + 64]);
    }
    __syncthreads();   // eluv[jc&1] ready (dbuf protects against next-iter rewrite)

    // ---- GEMM2: acc2 += ELU-chunk @ W2[jc*64:+64, w*64:+64] ----
    bf16x8 bw2b[4];
    #pragma unroll
    for (int q = 0; q < 4; ++q)
      bw2b[q] = *(const bf16x8*)(w2p + (size_t)q*16*1024 + 32);

    {
      int jb = l4*16;
      #pragma unroll
      for (int rt = 0; rt < 4; ++rt){
        int row = rt*16 + l15;
        bf16x8 a2 = *(const bf16x8*)(eb + row*128 + (jb ^ swz));
        #pragma unroll
        for (int q = 0; q < 4; ++q)
          acc2[rt][q] = mfma16(a2, bw2a[q], acc2[rt][q]);
      }
      jb = 64 + l4*16;
      #pragma unroll
      for (int rt = 0; rt < 4; ++rt){
        int row = rt*16 + l15;
        bf16x8 a2 = *(const bf16x8*)(eb + row*128 + (jb ^ swz));
        #pragma unroll
        for (int q = 0; q < 4; ++q)
          acc2[rt][q] = mfma16(a2, bw2b[q], acc2[rt][q]);
      }
    }
  }

  // ---- epilogue (R5 exact): + b2, E-mask, + h_e (fp32, global), store ----
  float bias[4];
  #pragma unroll
  for (int q = 0; q < 4; ++q) bias[q] = b2[w*64 + q*16 + l15];
  #pragma unroll
  for (int rt = 0; rt < 4; ++rt){
    #pragma unroll
    for (int reg = 0; reg < 4; ++reg){
      int row = rt*16 + l4*4 + reg;
      size_t grow = (size_t)(grow0 + row);
      int2 ep = *(const int2*)(Em + grow*2);
      const float* hep = he + grow*256 + w*64 + l15;
      float* op = out + grow*256 + w*64 + l15;
      #pragma unroll
      for (int q = 0; q < 4; ++q){
        float v = (ep.y == 1) ? (acc2[rt][q][reg] + bias[q]) : 0.f;
        op[q*16] = v + hep[q*16];
      }
    }
  }
}

extern "C" void kernel_launch(void* const* d_in, const int* in_sizes, int n_in,
                              void* d_out, int out_size, void* d_ws, size_t ws_size,
                              hipStream_t stream)
{
  const float* u   = (const float*)d_in[0];
  const float* h_v = (const float*)d_in[1];
  const float* h_e = (const float*)d_in[2];
  const float* V   = (const float*)d_in[3];
  const int*   E   = (const int*)d_in[4];
  const float* W1  = (const float*)d_in[5];
  const float* b1  = (const float*)d_in[6];
  const float* W2  = (const float*)d_in[7];
  const float* b2  = (const float*)d_in[8];
  float* out = (float*)d_out;

  char* ws = (char*)d_ws;
  short* w1t  = (short*)(ws);                               // 2 MB   bf16 W1^T [1024][1024]
  short* w2t  = (short*)(ws + (2u<<20));                    // 512KB  bf16 W2^T [256][1024]
  short* hvb  = (short*)(ws + (2u<<20) + (512u<<10));       // 256KB  bf16 masked h_v
  short* ub   = (short*)(ws + (2u<<20) + (768u<<10));       // 2KB    bf16 u
  short* sbuf = (short*)(ws + (3u<<20));                    // 1 MB   bf16 s [512][1024]
  short* tbuf = (short*)(ws + (4u<<20));                    // 1 MB   bf16 tT [1024][512]

  transpose_bf<<<1024, 256, 0, stream>>>(W1, w1t, 1024, 1024);
  transpose_bf<<<256,  256, 0, stream>>>(W2, w2t, 1024, 256);
  prep_hv<<<516, 256, 0, stream>>>(h_v, V, u, hvb, ub);
  prep_st<<<256, 256, 0, stream>>>(hvb, ub, w1t, b1, sbuf, tbuf);
  fused_edge<<<1024, 256, 0, stream>>>(h_e,
                                       (const unsigned short*)sbuf,
                                       (const unsigned short*)tbuf,
                                       w1t, w2t, b2, E, out);
}

// Round 11
// 181.651 us; speedup vs baseline: 1.8448x; 1.1833x over previous
//
#include <hip/hip_runtime.h>
#include <stdint.h>

#define DEVI __device__ __forceinline__

typedef short bf16x8 __attribute__((ext_vector_type(8)));
typedef float f32x4  __attribute__((ext_vector_type(4)));

DEVI short f2bf(float f){
  union { float f; uint32_t u; } un; un.f = f;
  uint32_t u = un.u;
  u += 0x7fffu + ((u >> 16) & 1u);   // RNE
  return (short)(u >> 16);
}
DEVI float bf2f(uint32_t us){
  union { uint32_t u; float f; } x; x.u = us << 16; return x.f;
}

DEVI f32x4 mfma16(bf16x8 a, bf16x8 b, f32x4 c){
  return __builtin_amdgcn_mfma_f32_16x16x32_bf16(a, b, c, 0, 0, 0);
}

// ---------- prep: transpose fp32 [R][C] -> bf16 [C][R] ----------
__global__ void transpose_bf(const float* __restrict__ W, short* __restrict__ WT,
                             int R, int C){
  __shared__ float tile[32][33];
  int ctiles = C >> 5;
  int bi = blockIdx.x / ctiles, bj = blockIdx.x % ctiles;
  int tx = threadIdx.x & 31, ty = threadIdx.x >> 5;
  #pragma unroll
  for (int r = 0; r < 4; ++r){
    int i = bi*32 + ty + r*8;
    tile[ty + r*8][tx] = W[(size_t)i*C + bj*32 + tx];
  }
  __syncthreads();
  #pragma unroll
  for (int r = 0; r < 4; ++r){
    int j = bj*32 + ty + r*8;
    WT[(size_t)j*R + bi*32 + tx] = f2bf(tile[tx][ty + r*8]);
  }
}

// ---------- prep: hvb = bf16(h_v * V), ub = bf16(u) ----------
__global__ void prep_hv(const float* __restrict__ hv, const float* __restrict__ V,
                        const float* __restrict__ u, short* __restrict__ hvb,
                        short* __restrict__ ub){
  int idx = blockIdx.x*256 + threadIdx.x;
  if (idx < 512*256){
    int r = idx >> 8;
    hvb[idx] = f2bf(hv[idx] * V[r]);
  } else if (idx < 512*256 + 1024){
    int i2 = idx - 512*256;
    ub[i2] = f2bf(u[i2]);
  }
}

// ---------- prep: s[(k,n)][j] = hv*W1[0:256] + u*W1[512:768] + b1   (bf16, row-major)
//                  tT[j][(k,m)] = hv*W1[256:512]                     (bf16, TRANSPOSED)
__global__ __launch_bounds__(256) void prep_st(
    const short* __restrict__ hvb, const short* __restrict__ ub,
    const short* __restrict__ w1t, const float* __restrict__ b1,
    short* __restrict__ sbuf, short* __restrict__ tbuf)
{
  const int bid = blockIdx.x;
  const int st = bid >> 7;           // 0 = s, 1 = t
  const int rt8 = (bid >> 4) & 7;    // 8 row tiles of 64 over 512 rows
  const int ctile = bid & 15;        // 16 col tiles of 64 over 1024 cols
  const int r0 = rt8 << 6, j0 = ctile << 6;
  const int tid = threadIdx.x;
  const int w = tid >> 6, l = tid & 63;
  const int l15 = l & 15, l4 = l >> 4;
  __shared__ short A[64*256];
  __shared__ short Stile[64][64];
  for (int q = 0; q < 8; ++q){
    int id = tid + (q << 8);
    int row = id >> 5, c8 = id & 31;
    bf16x8 v = *(const bf16x8*)(hvb + (size_t)(r0 + row)*256 + c8*8);
    *(bf16x8*)((char*)A + row*512 + ((c8*16) ^ ((row & 7) << 4))) = v;
  }
  __syncthreads();
  const int wr = w >> 1, wc = w & 1;
  const int rowbase = wr << 5, colbase = wc << 5;
  const int swzA = (l15 & 7) << 4;
  f32x4 acc[2][2];
  acc[0][0]=0; acc[0][1]=0; acc[1][0]=0; acc[1][1]=0;
  const int ioff = st ? 256 : 0;
  const short* w1p = w1t + (size_t)(j0 + colbase + l15)*1024 + ioff + l4*8;
  const char* ap0 = (const char*)A + (rowbase + l15)*512;
  const char* ap1 = ap0 + 16*512;
  #pragma unroll
  for (int kk = 0; kk < 8; ++kk){
    int ib = kk*64 + l4*16;
    bf16x8 a0 = *(const bf16x8*)(ap0 + (ib ^ swzA));
    bf16x8 a1 = *(const bf16x8*)(ap1 + (ib ^ swzA));
    bf16x8 b0 = *(const bf16x8*)(w1p + kk*32);
    bf16x8 b1v = *(const bf16x8*)(w1p + 16*1024 + kk*32);
    acc[0][0] = mfma16(a0, b0, acc[0][0]);
    acc[1][0] = mfma16(a1, b0, acc[1][0]);
    acc[0][1] = mfma16(a0, b1v, acc[0][1]);
    acc[1][1] = mfma16(a1, b1v, acc[1][1]);
  }
  if (st == 0){
    const int kb = r0 >> 7;
    const short* up = ub + kb*256 + l4*8;
    const short* w1pu = w1t + (size_t)(j0 + colbase + l15)*1024 + 512 + l4*8;
    #pragma unroll
    for (int kk = 0; kk < 8; ++kk){
      bf16x8 au = *(const bf16x8*)(up + kk*32);
      bf16x8 b0 = *(const bf16x8*)(w1pu + kk*32);
      bf16x8 b1v = *(const bf16x8*)(w1pu + 16*1024 + kk*32);
      acc[0][0] = mfma16(au, b0, acc[0][0]);
      acc[1][0] = mfma16(au, b0, acc[1][0]);
      acc[0][1] = mfma16(au, b1v, acc[0][1]);
      acc[1][1] = mfma16(au, b1v, acc[1][1]);
    }
  }
  #pragma unroll
  for (int r = 0; r < 2; ++r){
    #pragma unroll
    for (int c = 0; c < 2; ++c){
      int jl = colbase + c*16 + l15;
      float badd = st ? 0.f : b1[j0 + jl];
      #pragma unroll
      for (int reg = 0; reg < 4; ++reg){
        int rowl = rowbase + r*16 + l4*4 + reg;
        short v = f2bf(acc[r][c][reg] + badd);
        if (st == 0) Stile[rowl][jl] = v;
        else         Stile[jl][rowl] = v;
      }
    }
  }
  __syncthreads();
  {
    int a = tid >> 2, ch = (tid & 3) << 4;
    bf16x8 v0 = *(const bf16x8*)(&Stile[a][ch]);
    bf16x8 v1 = *(const bf16x8*)(&Stile[a][ch + 8]);
    short* dst = (st == 0)
      ? (sbuf + (size_t)(r0 + a)*1024 + j0 + ch)
      : (tbuf + (size_t)(j0 + a)*512  + r0 + ch);
    *(bf16x8*)(dst)     = v0;
    *(bf16x8*)(dst + 8) = v1;
  }
}

// ---------- main fused kernel: K-PAIR structure ----------
// block = (kp, n, m-half): TWO batch k's (k0,k0+1) x 64 m-rows = 128 logical rows.
// 512 blocks x 512 threads (8 waves), 1 block/CU, LDS 128.5 KB.
// Weights shared across the k-pair: weight-load:MFMA ratio and barrier count
// both halve vs the 64-row structure (which plateaued at 209-222us, MfmaUtil 13%).
// Per phase (128 hidden cols): GEMM1 wave w owns cols w*16..+16, all 128 rows;
// GEMM2 wave w owns out cols w*32..+32, all 128 rows. One barrier per phase.
__global__ __launch_bounds__(512, 2) void fused_edge(
    const float* __restrict__ he, const unsigned short* __restrict__ sb,
    const unsigned short* __restrict__ tbT, const short* __restrict__ w1t,
    const short* __restrict__ w2t, const float* __restrict__ b2,
    const int* __restrict__ Em, float* __restrict__ out)
{
  const int bo = blockIdx.x;
  const int b = ((bo & 7) << 6) | (bo >> 3);   // XCD swizzle, bijective (512%8==0)
  const int kp = b >> 8;                       // k-pair index 0..1
  const int n  = (b >> 1) & 127;
  const int m0 = (b & 1) << 6;
  const int k0 = kp << 1;
  const int tid = threadIdx.x;
  const int w = tid >> 6, l = tid & 63;
  const int l15 = l & 15, l4 = l >> 4;

  __shared__ short heb[128*256];       // 64 KB  bf16 h_e (2 k's), XOR-swizzled
  __shared__ short eluv[2][128*128];   // 64 KB  dbuf ELU chunk (128 rows x 128 cols)
  __shared__ int   emask[128];

  // grow(row) = base0 + (row>>6)*16384 + (row&63)   [row<64 -> k0, else k0+1]
  const int base0 = (k0*128 + n)*128 + m0;

  // stage h_e -> bf16 LDS: 4096 chunks of 8, 8 per thread
  #pragma unroll
  for (int q = 0; q < 8; ++q){
    int id = tid + (q << 9);
    int row = id >> 5, c8 = id & 31;
    size_t grow = (size_t)base0 + (row >> 6)*16384 + (row & 63);
    const float4* p = (const float4*)(he + grow*256 + c8*8);
    float4 a4 = p[0], b4 = p[1];
    union { bf16x8 v; short s[8]; } pk;
    pk.s[0]=f2bf(a4.x); pk.s[1]=f2bf(a4.y); pk.s[2]=f2bf(a4.z); pk.s[3]=f2bf(a4.w);
    pk.s[4]=f2bf(b4.x); pk.s[5]=f2bf(b4.y); pk.s[6]=f2bf(b4.z); pk.s[7]=f2bf(b4.w);
    *(bf16x8*)((char*)heb + row*512 + ((c8*16) ^ ((row & 7) << 4))) = pk.v;
  }
  if (tid < 128)
    emask[tid] = Em[((size_t)base0 + (tid >> 6)*16384 + (tid & 63))*2 + 1];
  __syncthreads();

  f32x4 acc2[8][2];
  #pragma unroll
  for (int i = 0; i < 8; ++i){ acc2[i][0] = 0; acc2[i][1] = 0; }

  const unsigned short* srow0 = sb + (size_t)(k0*128 + n)*1024;
  const unsigned short* srow1 = srow0 + 128*1024;
  const int tcol0 = k0*128 + m0;       // tT col base, rows 0-63
  const int tcol1 = tcol0 + 128;       // rows 64-127
  const char* hb = (const char*)heb;
  const int swz = (l15 & 7) << 4;

  union u4 { ushort4 v; unsigned short s[4]; };

  // ---- prologue: loads for ph = 0 ----
  bf16x8 bw1[8];
  {
    const short* w1p = w1t + (size_t)(w*16 + l15)*1024 + 768 + l4*8;
    #pragma unroll
    for (int kk = 0; kk < 8; ++kk) bw1[kk] = *(const bf16x8*)(w1p + kk*32);
  }
  u4 t4[8];
  #pragma unroll
  for (int rt = 0; rt < 8; ++rt){
    int tc = (rt < 4) ? (tcol0 + rt*16) : (tcol1 + (rt - 4)*16);
    t4[rt].v = *(const ushort4*)(tbT + (size_t)(w*16 + l15)*512 + tc + l4*4);
  }
  float sv0 = bf2f(srow0[w*16 + l15]);
  float sv1 = bf2f(srow1[w*16 + l15]);

  for (int ph = 0; ph < 8; ++ph){
    const int jcol = ph*128 + w*16 + l15;

    // ---- GEMM1: z1[128 x 16(w)] = heb @ W1[768:1024, jcol] ----
    f32x4 acc1[8];
    #pragma unroll
    for (int i = 0; i < 8; ++i) acc1[i] = 0;
    #pragma unroll
    for (int kk = 0; kk < 8; ++kk){
      int ib = kk*64 + l4*16;
      #pragma unroll
      for (int rt = 0; rt < 8; ++rt){
        int row = rt*16 + l15;
        bf16x8 a = *(const bf16x8*)(hb + row*512 + (ib ^ swz));
        acc1[rt] = mfma16(a, bw1[kk], acc1[rt]);
      }
    }

    // ---- issue all W2 fragments for this phase (consumed after barrier) ----
    const short* w2p = w2t + (size_t)(w*32 + l15)*1024 + ph*128 + l4*8;
    bf16x8 bw2[2][4];
    #pragma unroll
    for (int ct = 0; ct < 2; ++ct)
      #pragma unroll
      for (int kk = 0; kk < 4; ++kk)
        bw2[ct][kk] = *(const bf16x8*)(w2p + (size_t)ct*16*1024 + kk*32);

    // ---- reload bw1 for ph+1 (regs dead after GEMM1) ----
    if (ph < 7){
      const short* w1p = w1t + (size_t)(jcol + 128)*1024 + 768 + l4*8;
      #pragma unroll
      for (int kk = 0; kk < 8; ++kk) bw1[kk] = *(const bf16x8*)(w1p + kk*32);
    }

    // ---- ELU: z1 + s + t -> bf16 LDS dbuf (swizzled) ----
    char* eb = (char*)(&eluv[ph & 1][0]);
    const int cb = (w*16 + l15)*2;
    #pragma unroll
    for (int rt = 0; rt < 8; ++rt){
      float sv = (rt < 4) ? sv0 : sv1;
      #pragma unroll
      for (int reg = 0; reg < 4; ++reg){
        int row = rt*16 + l4*4 + reg;
        float v = acc1[rt][reg] + sv + bf2f(t4[rt].s[reg]);
        v = v > 0.f ? v : (__expf(v) - 1.f);
        *(short*)(eb + row*256 + (cb ^ ((row & 7) << 4))) = f2bf(v);
      }
    }

    // ---- prefetch t4/sv for ph+1 ----
    if (ph < 7){
      #pragma unroll
      for (int rt = 0; rt < 8; ++rt){
        int tc = (rt < 4) ? (tcol0 + rt*16) : (tcol1 + (rt - 4)*16);
        t4[rt].v = *(const ushort4*)(tbT + (size_t)(jcol + 128)*512 + tc + l4*4);
      }
      sv0 = bf2f(srow0[jcol + 128]);
      sv1 = bf2f(srow1[jcol + 128]);
    }
    __syncthreads();   // eluv[ph&1] ready (1 barrier/phase; dbuf + wave-skew bound)

    // ---- GEMM2: acc2 += ELU-chunk @ W2[ph*128:+128, w*32:+32] ----
    #pragma unroll
    for (int kk = 0; kk < 4; ++kk){
      int jb = kk*64 + l4*16;
      #pragma unroll
      for (int rt = 0; rt < 8; ++rt){
        int row = rt*16 + l15;
        bf16x8 a2 = *(const bf16x8*)(eb + row*256 + (jb ^ swz));
        acc2[rt][0] = mfma16(a2, bw2[0][kk], acc2[rt][0]);
        acc2[rt][1] = mfma16(a2, bw2[1][kk], acc2[rt][1]);
      }
    }
  }

  // ---- epilogue: + b2, E-mask, residual from LDS heb (bf16), store ----
  const float bias0 = b2[w*32 + l15];
  const float bias1 = b2[w*32 + 16 + l15];
  #pragma unroll
  for (int rt = 0; rt < 8; ++rt){
    #pragma unroll
    for (int reg = 0; reg < 4; ++reg){
      int row = rt*16 + l4*4 + reg;
      int e = emask[row];
      size_t grow = (size_t)base0 + (row >> 6)*16384 + (row & 63);
      float* op = out + grow*256 + w*32 + l15;
      const char* hrow = hb + row*512;
      int sw = (row & 7) << 4;
      float hv0 = bf2f(*(const unsigned short*)(hrow + (((w*32 + l15)*2) ^ sw)));
      float hv1 = bf2f(*(const unsigned short*)(hrow + (((w*32 + 16 + l15)*2) ^ sw)));
      op[0]  = ((e == 1) ? (acc2[rt][0][reg] + bias0) : 0.f) + hv0;
      op[16] = ((e == 1) ? (acc2[rt][1][reg] + bias1) : 0.f) + hv1;
    }
  }
}

extern "C" void kernel_launch(void* const* d_in, const int* in_sizes, int n_in,
                              void* d_out, int out_size, void* d_ws, size_t ws_size,
                              hipStream_t stream)
{
  const float* u   = (const float*)d_in[0];
  const float* h_v = (const float*)d_in[1];
  const float* h_e = (const float*)d_in[2];
  const float* V   = (const float*)d_in[3];
  const int*   E   = (const int*)d_in[4];
  const float* W1  = (const float*)d_in[5];
  const float* b1  = (const float*)d_in[6];
  const float* W2  = (const float*)d_in[7];
  const float* b2  = (const float*)d_in[8];
  float* out = (float*)d_out;

  char* ws = (char*)d_ws;
  short* w1t  = (short*)(ws);                               // 2 MB   bf16 W1^T [1024][1024]
  short* w2t  = (short*)(ws + (2u<<20));                    // 512KB  bf16 W2^T [256][1024]
  short* hvb  = (short*)(ws + (2u<<20) + (512u<<10));       // 256KB  bf16 masked h_v
  short* ub   = (short*)(ws + (2u<<20) + (768u<<10));       // 2KB    bf16 u
  short* sbuf = (short*)(ws + (3u<<20));                    // 1 MB   bf16 s [512][1024]
  short* tbuf = (short*)(ws + (4u<<20));                    // 1 MB   bf16 tT [1024][512]

  transpose_bf<<<1024, 256, 0, stream>>>(W1, w1t, 1024, 1024);
  transpose_bf<<<256,  256, 0, stream>>>(W2, w2t, 1024, 256);
  prep_hv<<<516, 256, 0, stream>>>(h_v, V, u, hvb, ub);
  prep_st<<<256, 256, 0, stream>>>(hvb, ub, w1t, b1, sbuf, tbuf);
  fused_edge<<<512, 512, 0, stream>>>(h_e,
                                      (const unsigned short*)sbuf,
                                      (const unsigned short*)tbuf,
                                      w1t, w2t, b2, E, out);
}